// Round 8
// baseline (373.813 us; speedup 1.0000x reference)
//
#include <hip/hip_runtime.h>
#include <hip/hip_bf16.h>

// B=8,G=16,N=1024,C=256.
//  q = x @ Wfc^T (bias dropped: constant along softmax axis n)
//  atten = softmax over n (no max-shift: q~N(0,1), exp safe in fp32)
//  T[c,d] = sum_n atten[n,c]*x[n,c]*v[n,d];  out = Wvn @ T per bg.
// R8: true register cut for occupancy. prep kernel converts Wfc->bf16 table in
// ws (+ zeroes wsacc/counters/out). Kernel1: RT=64 tiles (acc 16 regs), per-ks
// B-frag loads from the bf16 table (no persistent 64-reg array), grid 2048
// (bg x ctile x 4 n-quarters). Last block per (bg,ctile) (atomic counter)
// normalizes T and adds the VN partial to out.

#define NQ 1024
#define CQ 256
#define CT 64
#define RT 64           // rows per n-tile
#define NTB 4           // tiles per block (256 rows)
#define NH 4            // n-quarters
#define XS 136          // xs row stride (bf16): 272 B (16B-mult)

typedef __attribute__((ext_vector_type(8))) short bf16x8;
typedef __attribute__((ext_vector_type(4))) float f32x4;

__device__ __forceinline__ ushort2 pk2(float a, float b) {
    __hip_bfloat162 h = __float22bfloat162_rn(make_float2(a, b));  // v_cvt_pk_bf16_f32
    ushort2 r;
    __builtin_memcpy(&r, &h, sizeof(r));
    return r;
}
__device__ __forceinline__ float bf2f(ushort h) {
    union { unsigned u; float f; } v; v.u = ((unsigned)h) << 16;
    return v.f;
}

// ws layout: [0,512K) wsacc f32[128][256][4]; [512K,514K) counters u32[512];
//            [514K, 514K+128K) wfb bf16[256][256]
#define WSACC_F4   32768     // float4 count
#define CNT_OFF    (512 * 1024)
#define WFB_OFF    (CNT_OFF + 2048)

__global__ __launch_bounds__(256)
void prep(const float* __restrict__ Wfc, ushort* __restrict__ wfb,
          float* __restrict__ wsacc, unsigned* __restrict__ cnt,
          float* __restrict__ out) {
    const int tid = blockIdx.x * 256 + threadIdx.x;   // grid 128 -> 32768 threads
    reinterpret_cast<float4*>(wsacc)[tid] = (float4){0.f, 0.f, 0.f, 0.f};
    if (tid < 512) cnt[tid] = 0u;
    if (tid < 24576) reinterpret_cast<float4*>(out)[tid] = (float4){0.f, 0.f, 0.f, 0.f};
    if (tid < 16384) {
        float4 v = reinterpret_cast<const float4*>(Wfc)[tid];
        ushort2 a = pk2(v.x, v.y), b = pk2(v.z, v.w);
        ushort4 pk = { a.x, a.y, b.x, b.y };
        reinterpret_cast<ushort4*>(wfb)[tid] = pk;
    }
}

__global__ __launch_bounds__(256, 2)
void fused_attn_pool_mfma(const float* __restrict__ x, const float* __restrict__ vs,
                          const ushort* __restrict__ wfb, float* __restrict__ wsacc,
                          unsigned* __restrict__ cnt, const float* __restrict__ Wvn,
                          float* __restrict__ out) {
    __shared__ __align__(16) ushort xs[RT * XS];   // 17408 B
    __shared__ __align__(16) float  vsm[RT * 3];   // 768 B
    __shared__ f32x4 red[4][32];                   // 2048 B
    __shared__ float Tsm[CT][3];                   // 768 B
    __shared__ int flag;

    const int t = threadIdx.x;
    const int id = blockIdx.x;
    // id bits: [2:0]=xcd-slot, [6:3]=sub(ctile,nh), [10:7]=hi.
    // All 16 blocks of one bg share id mod 8 -> same XCD -> x L2 reuse.
    const int sub = (id >> 3) & 15;
    const int bg = (id & 7) + ((id >> 7) << 3);
    const int ctile = sub & 3;
    const int nh = sub >> 2;
    const int c0 = ctile * CT;
    const int own = ctile >> 1;            // K-chunk containing this block's columns

    const int w = t >> 6, lane = t & 63;
    const int quad = lane >> 4, l16 = lane & 15;
    const int rstrip = (w & 1) * 32;       // wave rows within tile
    const int cstrip = (w >> 1) * 32;      // wave cols within CT
    const int myc0 = c0 + cstrip + l16;    // B-frag row (this lane's column)

    const float* xb = x + (size_t)bg * NQ * CQ;
    const float* vb = vs + (size_t)bg * NQ * 3;

    // per-lane running partials: col = c0 + cstrip + ci*16 + l16
    float rZ[2] = {0.f, 0.f}, rS0[2] = {0.f, 0.f}, rS1[2] = {0.f, 0.f}, rS2[2] = {0.f, 0.f};

    for (int nt = 0; nt < NTB; ++nt) {
        const int n0 = nh * (NTB * RT) + nt * RT;
        if (t < 48) {   // v tile: 192 floats (visible after first chunk barrier)
            reinterpret_cast<float4*>(vsm)[t] =
                reinterpret_cast<const float4*>(vb + (size_t)n0 * 3)[t];
        }

        f32x4 acc[2][2];
        #pragma unroll
        for (int m = 0; m < 2; ++m)
            #pragma unroll
            for (int ci = 0; ci < 2; ++ci) acc[m][ci] = (f32x4){0.f, 0.f, 0.f, 0.f};

        #pragma unroll
        for (int kc = 0; kc < 2; ++kc) {
            const int ch = (kc == 0) ? (own ^ 1) : own;   // own chunk staged LAST
            const int kc0 = ch * 128;
            // stage x chunk: 64 rows x 128 k fp32 -> bf16 (2048 float4, 8/thread)
            #pragma unroll
            for (int p = 0; p < 8; ++p) {
                int idx = p * 256 + t;
                int row = idx >> 5, k4 = idx & 31;
                float4 v4 = *reinterpret_cast<const float4*>(
                    xb + (size_t)(n0 + row) * CQ + kc0 + k4 * 4);
                ushort2 a0 = pk2(v4.x, v4.y), a1 = pk2(v4.z, v4.w);
                ushort4 pk = { a0.x, a0.y, a1.x, a1.y };
                *reinterpret_cast<ushort4*>(&xs[row * XS + k4 * 4]) = pk;
            }
            __syncthreads();
            #pragma unroll
            for (int ks = 0; ks < 4; ++ks) {
                const int kk = ks * 32 + quad * 8;
                // per-ks B-frags straight from L2-hot bf16 table (8 transient regs)
                bf16x8 b0 = *reinterpret_cast<const bf16x8*>(&wfb[(size_t)myc0 * CQ + kc0 + kk]);
                bf16x8 b1 = *reinterpret_cast<const bf16x8*>(&wfb[(size_t)(myc0 + 16) * CQ + kc0 + kk]);
                #pragma unroll
                for (int m = 0; m < 2; ++m) {
                    bf16x8 a = *reinterpret_cast<const bf16x8*>(
                        &xs[(rstrip + m * 16 + l16) * XS + kk]);
                    acc[m][0] = __builtin_amdgcn_mfma_f32_16x16x32_bf16(a, b0, acc[m][0], 0, 0, 0);
                    acc[m][1] = __builtin_amdgcn_mfma_f32_16x16x32_bf16(a, b1, acc[m][1], 0, 0, 0);
                }
            }
            if (kc == 0) __syncthreads();   // xs restaged; after kc=1, phase B reads it
        }
        // xs holds chunk `own`; block's own columns at local offset:
        const int xcb = (ctile & 1) * 64 + cstrip;

        // ---- phase B: e = exp(q); accumulate Z, S ----
        #pragma unroll
        for (int m = 0; m < 2; ++m) {
            const int rbase = rstrip + m * 16 + quad * 4;
            float v0[4], v1[4], v2[4];
            #pragma unroll
            for (int r = 0; r < 4; ++r) {
                v0[r] = vsm[(rbase + r) * 3 + 0];
                v1[r] = vsm[(rbase + r) * 3 + 1];
                v2[r] = vsm[(rbase + r) * 3 + 2];
            }
            #pragma unroll
            for (int ci = 0; ci < 2; ++ci) {
                const int xc = xcb + ci * 16 + l16;
                #pragma unroll
                for (int r = 0; r < 4; ++r) {
                    float e = __expf(acc[m][ci][r]);
                    float xv = bf2f(xs[(rbase + r) * XS + xc]);
                    rZ[ci] += e;
                    float p = e * xv;
                    rS0[ci] = fmaf(p, v0[r], rS0[ci]);
                    rS1[ci] = fmaf(p, v1[r], rS1[ci]);
                    rS2[ci] = fmaf(p, v2[r], rS2[ci]);
                }
            }
        }
        __syncthreads();   // protect xs/vsm before next tile's staging
    }

    // ---- reduction: over quads (shfl), then over row-strip wave pairs (LDS) ----
    #pragma unroll
    for (int ci = 0; ci < 2; ++ci) {
        float z = rZ[ci], s0 = rS0[ci], s1 = rS1[ci], s2 = rS2[ci];
        #pragma unroll
        for (int off = 16; off < 64; off <<= 1) {
            z  += __shfl_xor(z,  off);
            s0 += __shfl_xor(s0, off);
            s1 += __shfl_xor(s1, off);
            s2 += __shfl_xor(s2, off);
        }
        if (quad == 0) red[w][ci * 16 + l16] = (f32x4){z, s0, s1, s2};
    }
    __syncthreads();
    if (t < CT) {
        const int s = t >> 5, cc = t & 31;
        f32x4 a = red[2 * s][cc], b = red[2 * s + 1][cc];
        float* p = wsacc + ((size_t)bg * CQ + c0 + t) * 4;
        atomicAdd(p + 0, a[0] + b[0]);
        atomicAdd(p + 1, a[1] + b[1]);
        atomicAdd(p + 2, a[2] + b[2]);
        atomicAdd(p + 3, a[3] + b[3]);
    }
    __syncthreads();   // all wsacc atomics issued & drained (vmcnt) before counter
    if (t == 0) {
        __threadfence();
        flag = (int)atomicAdd(&cnt[bg * 4 + ctile], 1u);
    }
    __syncthreads();
    if (flag != NH - 1) return;

    // ---- last block of this (bg,ctile): normalize T, add VN partial to out ----
    if (t < CT) {
        __threadfence();
        const float* p = wsacc + ((size_t)bg * CQ + c0 + t) * 4;
        float Z  = __hip_atomic_load(p + 0, __ATOMIC_RELAXED, __HIP_MEMORY_SCOPE_AGENT);
        float S0 = __hip_atomic_load(p + 1, __ATOMIC_RELAXED, __HIP_MEMORY_SCOPE_AGENT);
        float S1 = __hip_atomic_load(p + 2, __ATOMIC_RELAXED, __HIP_MEMORY_SCOPE_AGENT);
        float S2 = __hip_atomic_load(p + 3, __ATOMIC_RELAXED, __HIP_MEMORY_SCOPE_AGENT);
        float inv = 1.f / Z;
        Tsm[t][0] = S0 * inv; Tsm[t][1] = S1 * inv; Tsm[t][2] = S2 * inv;
    }
    __syncthreads();
    {
        const float* wr = Wvn + (size_t)t * CQ + c0;   // row o = t
        float a0 = 0.f, a1 = 0.f, a2 = 0.f;
        #pragma unroll
        for (int c = 0; c < CT; c += 4) {
            float4 w4 = *reinterpret_cast<const float4*>(wr + c);
            a0 += w4.x * Tsm[c + 0][0] + w4.y * Tsm[c + 1][0]
                + w4.z * Tsm[c + 2][0] + w4.w * Tsm[c + 3][0];
            a1 += w4.x * Tsm[c + 0][1] + w4.y * Tsm[c + 1][1]
                + w4.z * Tsm[c + 2][1] + w4.w * Tsm[c + 3][1];
            a2 += w4.x * Tsm[c + 0][2] + w4.y * Tsm[c + 1][2]
                + w4.z * Tsm[c + 2][2] + w4.w * Tsm[c + 3][2];
        }
        float* op = out + ((size_t)bg * CQ + t) * 3;
        atomicAdd(&op[0], a0);
        atomicAdd(&op[1], a1);
        atomicAdd(&op[2], a2);
    }
}

extern "C" void kernel_launch(void* const* d_in, const int* in_sizes, int n_in,
                              void* d_out, int out_size, void* d_ws, size_t ws_size,
                              hipStream_t stream) {
    const float* x   = (const float*)d_in[0];  // [8,16,1024,256]
    const float* vs  = (const float*)d_in[1];  // [8,16,1,1024,3]
    const float* Wfc = (const float*)d_in[2];  // [256,256]
    // d_in[3] = b_fc: no effect under softmax, unused
    const float* Wvn = (const float*)d_in[4];  // [256,256]
    float* out = (float*)d_out;                // [8,16,256,3]

    char* ws = (char*)d_ws;
    float*    wsacc = (float*)ws;
    unsigned* cnt   = (unsigned*)(ws + CNT_OFF);
    ushort*   wfb   = (ushort*)(ws + WFB_OFF);

    prep<<<dim3(128), dim3(256), 0, stream>>>(Wfc, wfb, wsacc, cnt, out);
    fused_attn_pool_mfma<<<dim3(2048), dim3(256), 0, stream>>>(x, vs, wfb, wsacc, cnt, Wvn, out);
}